// Round 2
// baseline (714.603 us; speedup 1.0000x reference)
//
#include <hip/hip_runtime.h>
#include <hip/hip_bf16.h>

// Problem constants (B=4, T=4096, C=1024, NH=16, DH=128, DQKV=2048, DR=256)
#define TB 4
#define TT 4096
#define TC 1024
#define TNH 16
#define TDH 128
#define TDQKV 2048
#define TDR 256
#define RB 4096               // rows per batch chunk (= T)

typedef __attribute__((ext_vector_type(8))) short bfx8;
typedef __attribute__((ext_vector_type(4))) float fx4;

__device__ __forceinline__ unsigned short f2b(float f) {
    unsigned int u = __float_as_uint(f);
    unsigned int r = (u + 0x7fffu + ((u >> 16) & 1u)) >> 16;   // RNE
    return (unsigned short)r;
}
__device__ __forceinline__ float b2f(unsigned short h) {
    return __uint_as_float(((unsigned int)h) << 16);
}
__device__ __forceinline__ float sigm(float x) {
    return 1.0f / (1.0f + __expf(-x));
}

// ---------------- elementwise f32 -> bf16 (weights) ----------------
__global__ __launch_bounds__(256) void cvt_bf16(const float* __restrict__ in,
                                                unsigned short* __restrict__ out, int n) {
    int i = (blockIdx.x * 256 + threadIdx.x) * 4;
    if (i < n) {
        float4 v = *(const float4*)(in + i);
        out[i + 0] = f2b(v.x);
        out[i + 1] = f2b(v.y);
        out[i + 2] = f2b(v.z);
        out[i + 3] = f2b(v.w);
    }
}

// ---------------- RoPE cos/sin table [T][32] ----------------
__global__ __launch_bounds__(256) void rope_tab(float* __restrict__ ct, float* __restrict__ st) {
    int i = blockIdx.x * 256 + threadIdx.x;     // < T*32
    int t = i >> 5, j = i & 31;
    float fr = exp2f(-10.0f * (float)j / 31.0f);   // (1/1024)^(j/31)
    float th = (float)t * fr;
    ct[i] = cosf(th);
    st[i] = sinf(th);
}

// ---------------- RMSNorm(x) -> bf16, one block per row of 1024 ----------------
__global__ __launch_bounds__(256) void rmsnorm_x(const float* __restrict__ x,
                                                 unsigned short* __restrict__ xn) {
    int row = blockIdx.x;
    int tid = threadIdx.x;
    float4 v = *(const float4*)(x + (size_t)row * TC + tid * 4);
    float ss = v.x * v.x + v.y * v.y + v.z * v.z + v.w * v.w;
    #pragma unroll
    for (int o = 32; o > 0; o >>= 1) ss += __shfl_xor(ss, o);
    __shared__ float red[4];
    if ((tid & 63) == 0) red[tid >> 6] = ss;
    __syncthreads();
    float tot = red[0] + red[1] + red[2] + red[3];
    float sc = rsqrtf(tot * (1.0f / TC) + 1.1920929e-7f);
    unsigned short* o = xn + (size_t)row * TC + tid * 4;
    o[0] = f2b(v.x * sc); o[1] = f2b(v.y * sc); o[2] = f2b(v.z * sc); o[3] = f2b(v.w * sc);
}

// ---------------- bf16 GEMM: C[M,N] = A[M,K](lda) @ Bm[N,K]^T  (EPI=1: relu^2) ----------------
template <int EPI>
__global__ __launch_bounds__(256) void gemm_bt(const unsigned short* __restrict__ A, int lda,
                                               const unsigned short* __restrict__ Bm,
                                               unsigned short* __restrict__ C, int ldc,
                                               int M, int N, int K) {
    __shared__ unsigned short As[128][40];   // +8 pad: 80B row stride -> 2-way (free)
    __shared__ unsigned short Bs[128][40];
    const int m0 = blockIdx.y * 128;
    const int n0 = blockIdx.x * 128;
    const int tid = threadIdx.x;
    const int lane = tid & 63;
    const int w = tid >> 6;
    const int wr = w >> 1, wc = w & 1;       // wave -> 64x64 quadrant
    const int r16 = lane & 15;
    const int kk = (lane >> 4) * 8;          // k-base of this lane's fragment
    fx4 acc[4][4] = {};

    for (int k0 = 0; k0 < K; k0 += 32) {
        #pragma unroll
        for (int i = 0; i < 2; ++i) {
            int idx = tid + i * 256;         // 512 chunks of 8 bf16
            int row = idx >> 2, ch = (idx & 3) * 8;
            *(bfx8*)(&As[row][ch]) = *(const bfx8*)(A + (size_t)(m0 + row) * lda + k0 + ch);
            *(bfx8*)(&Bs[row][ch]) = *(const bfx8*)(Bm + (size_t)(n0 + row) * K + k0 + ch);
        }
        __syncthreads();
        bfx8 af[4], bfr[4];
        #pragma unroll
        for (int mi = 0; mi < 4; mi++) af[mi] = *(const bfx8*)(&As[wr * 64 + mi * 16 + r16][kk]);
        #pragma unroll
        for (int ni = 0; ni < 4; ni++) bfr[ni] = *(const bfx8*)(&Bs[wc * 64 + ni * 16 + r16][kk]);
        #pragma unroll
        for (int mi = 0; mi < 4; mi++)
            #pragma unroll
            for (int ni = 0; ni < 4; ni++)
                acc[mi][ni] = __builtin_amdgcn_mfma_f32_16x16x32_bf16(af[mi], bfr[ni], acc[mi][ni], 0, 0, 0);
        __syncthreads();
    }

    const int rg = lane >> 4;
    #pragma unroll
    for (int mi = 0; mi < 4; mi++)
        #pragma unroll
        for (int ni = 0; ni < 4; ni++) {
            int col = n0 + wc * 64 + ni * 16 + r16;
            #pragma unroll
            for (int r = 0; r < 4; r++) {
                int row = m0 + wr * 64 + mi * 16 + rg * 4 + r;
                float v = acc[mi][ni][r];
                if (EPI == 1) { v = fmaxf(v, 0.0f); v *= v; }
                C[(size_t)row * ldc + col] = f2b(v);
            }
        }
}

// ---------------- q/k RMSNorm + RoPE, in-place on qkv chunk (bf16), one wave per 128-row ----
// qkvb layout: [RB][6144], col = which*2048 + h*128 + d  (which: 0=q,1=k,2=v); row == t
__global__ __launch_bounds__(256) void qk_post(unsigned short* __restrict__ qkv,
                                               const float* __restrict__ ct,
                                               const float* __restrict__ st) {
    int gri = blockIdx.x * 4 + (threadIdx.x >> 6);  // < RB*32 (q heads 0-15, k heads 16-31)
    int lane = threadIdx.x & 63;
    int t = gri >> 5;
    int h32 = gri & 31;
    size_t base = (size_t)t * 6144 + (size_t)h32 * 128;
    float e0 = b2f(qkv[base + lane]);        // dim l   (z1)
    float e1 = b2f(qkv[base + 64 + lane]);   // dim l+64 (z2)
    float ss = e0 * e0 + e1 * e1;
    #pragma unroll
    for (int o = 32; o > 0; o >>= 1) ss += __shfl_xor(ss, o);
    float sc = rsqrtf(ss * (1.0f / TDH) + 1.1920929e-7f);
    float z1 = e0 * sc, z2 = e1 * sc, o1, o2;
    if (lane < 32) {
        float c = ct[t * 32 + lane], s = st[t * 32 + lane];
        o1 = z1 * c + z2 * s;
        o2 = z2 * c - z1 * s;
    } else {                                  // freq==0 -> identity
        o1 = z1; o2 = z2;
    }
    qkv[base + lane] = f2b(o1);
    qkv[base + 64 + lane] = f2b(o2);
}

// ---------------- segmented scan phase A: segment sums of sigmoid(k)*v ----------------
// blocks: h*64 + s  (16 heads x 64 segments of 64 timesteps), 128 threads = d
__global__ __launch_bounds__(128) void scanA(const unsigned short* __restrict__ qkv,
                                             float* __restrict__ part) {
    int blk = blockIdx.x;
    int d = threadIdx.x;
    int s = blk & 63;
    int h = blk >> 6;
    size_t rowbase = (size_t)(s * 64) * 6144 + (size_t)h * 128 + d;
    const unsigned short* kp = qkv + rowbase + 2048;
    const unsigned short* vp = qkv + rowbase + 4096;
    float sum = 0.0f;
    #pragma unroll 8
    for (int t = 0; t < 64; ++t) {
        float kv = b2f(kp[(size_t)t * 6144]);
        float vv = b2f(vp[(size_t)t * 6144]);
        sum += sigm(kv) * vv;
    }
    part[(size_t)blk * 128 + d] = sum;
}

// ---------------- phase B: exclusive prefix over 64 segments per (h,d), in registers ----
__global__ __launch_bounds__(256) void scanB(float* __restrict__ part) {
    int idx = blockIdx.x * 256 + threadIdx.x;   // < 2048 chains
    int h = idx >> 7, d = idx & 127;
    float v[64];
    #pragma unroll
    for (int s = 0; s < 64; ++s) v[s] = part[((size_t)(h * 64 + s)) * 128 + d];
    float run = 0.0f;
    #pragma unroll
    for (int s = 0; s < 64; ++s) { float tv = v[s]; v[s] = run; run += tv; }
    #pragma unroll
    for (int s = 0; s < 64; ++s) part[((size_t)(h * 64 + s)) * 128 + d] = v[s];
}

// ---------------- phase C: running sum + y = relu(q)*sum, y IN-PLACE over q slice ----------
__global__ __launch_bounds__(128) void scanC(unsigned short* __restrict__ qkv,
                                             const float* __restrict__ part) {
    int blk = blockIdx.x;
    int d = threadIdx.x;
    int s = blk & 63;
    int h = blk >> 6;
    size_t rowbase = (size_t)(s * 64) * 6144 + (size_t)h * 128 + d;
    unsigned short* qp = qkv + rowbase;              // q slice; becomes y
    const unsigned short* kp = qkv + rowbase + 2048;
    const unsigned short* vp = qkv + rowbase + 4096;
    float sum = part[(size_t)blk * 128 + d];
    #pragma unroll 4
    for (int t = 0; t < 64; ++t) {
        float kv = b2f(kp[(size_t)t * 6144]);
        float vv = b2f(vp[(size_t)t * 6144]);
        sum += sigm(kv) * vv;
        float qv = b2f(qp[(size_t)t * 6144]);
        qp[(size_t)t * 6144] = f2b(fmaxf(qv, 0.0f) * sum);
    }
}

// ---------------- final: out = x + u*silu(g); uv lives in d_out slice (bf16), in-place per row ----
__global__ __launch_bounds__(256) void final_k(const float* __restrict__ x, float* __restrict__ out) {
    int row = blockIdx.x;
    int tid = threadIdx.x;
    const unsigned short* uv = (const unsigned short*)out;
    size_t ub = (size_t)row * 2048 + tid * 4;
    unsigned short u0 = uv[ub + 0], u1 = uv[ub + 1], u2 = uv[ub + 2], u3 = uv[ub + 3];
    unsigned short g0 = uv[ub + 1024], g1 = uv[ub + 1025], g2 = uv[ub + 1026], g3 = uv[ub + 1027];
    float4 xv = *(const float4*)(x + (size_t)row * TC + tid * 4);
    __syncthreads();   // all reads of this row done before any write (block owns the row)
    float4 o;
    {
        float g = b2f(g0), u = b2f(u0); o.x = xv.x + u * (g * sigm(g));
        g = b2f(g1); u = b2f(u1);       o.y = xv.y + u * (g * sigm(g));
        g = b2f(g2); u = b2f(u2);       o.z = xv.z + u * (g * sigm(g));
        g = b2f(g3); u = b2f(u3);       o.w = xv.w + u * (g * sigm(g));
    }
    *(float4*)(out + (size_t)row * TC + tid * 4) = o;
}

extern "C" void kernel_launch(void* const* d_in, const int* in_sizes, int n_in,
                              void* d_out, int out_size, void* d_ws, size_t ws_size,
                              hipStream_t stream) {
    (void)in_sizes; (void)n_in; (void)out_size; (void)ws_size;
    const float* x    = (const float*)d_in[0];
    const float* wq1  = (const float*)d_in[1];   // [256,1024]
    const float* wq2  = (const float*)d_in[2];   // [6144,256]
    const float* wc1  = (const float*)d_in[3];   // [256,2048]
    const float* wc2  = (const float*)d_in[4];   // [2048,256]
    float* out = (float*)d_out;

    char* ws = (char*)d_ws;
    size_t off = 0;
    auto alloc = [&](size_t bytes) -> void* {
        off = (off + 255) & ~(size_t)255;
        void* p = ws + off;
        off += bytes;
        return p;
    };
    // total ~70.3 MB
    unsigned short* qkvb = (unsigned short*)alloc((size_t)RB * 6144 * 2);   // 50.3 MB
    unsigned short* xnb  = (unsigned short*)alloc((size_t)RB * TC * 2);     //  8.4 MB
    unsigned short* hb   = (unsigned short*)alloc((size_t)RB * TDR * 2);    //  2.1 MB
    unsigned short* t1b  = (unsigned short*)alloc((size_t)RB * TDR * 2);    //  2.1 MB
    unsigned short* w1b  = (unsigned short*)alloc((size_t)TDR * TC * 2);
    unsigned short* w2b  = (unsigned short*)alloc((size_t)3 * TDQKV * TDR * 2);
    unsigned short* wp1b = (unsigned short*)alloc((size_t)TDR * TDQKV * 2);
    unsigned short* wp2b = (unsigned short*)alloc((size_t)2 * TC * TDR * 2);
    float* ct   = (float*)alloc((size_t)TT * 32 * 4);
    float* st   = (float*)alloc((size_t)TT * 32 * 4);
    float* part = (float*)alloc((size_t)TNH * 64 * 128 * 4);                // 0.5 MB

    // one-time setup (per call; cheap)
    cvt_bf16<<<(TDR * TC) / 1024, 256, 0, stream>>>(wq1, w1b, TDR * TC);
    cvt_bf16<<<(3 * TDQKV * TDR) / 1024, 256, 0, stream>>>(wq2, w2b, 3 * TDQKV * TDR);
    cvt_bf16<<<(TDR * TDQKV) / 1024, 256, 0, stream>>>(wc1, wp1b, TDR * TDQKV);
    cvt_bf16<<<(2 * TC * TDR) / 1024, 256, 0, stream>>>(wc2, wp2b, 2 * TC * TDR);
    rope_tab<<<(TT * 32) / 256, 256, 0, stream>>>(ct, st);

    for (int b = 0; b < TB; ++b) {
        const float* xb = x + (size_t)b * RB * TC;
        float* outb = out + (size_t)b * RB * TC;
        unsigned short* uvb = (unsigned short*)d_out + (size_t)b * RB * 2048;

        rmsnorm_x<<<RB, 256, 0, stream>>>(xb, xnb);
        gemm_bt<1><<<dim3(TDR / 128, RB / 128), 256, 0, stream>>>(
            xnb, TC, w1b, hb, TDR, RB, TDR, TC);
        gemm_bt<0><<<dim3(6144 / 128, RB / 128), 256, 0, stream>>>(
            hb, TDR, w2b, qkvb, 6144, RB, 6144, TDR);
        qk_post<<<(RB * 32) / 4, 256, 0, stream>>>(qkvb, ct, st);
        scanA<<<TNH * 64, 128, 0, stream>>>(qkvb, part);
        scanB<<<(TNH * 128) / 256, 256, 0, stream>>>(part);
        scanC<<<TNH * 64, 128, 0, stream>>>(qkvb, part);
        // gemm3: A = y (in-place q slice of qkvb), lda=6144, K=2048
        gemm_bt<0><<<dim3(TDR / 128, RB / 128), 256, 0, stream>>>(
            qkvb, 6144, wp1b, t1b, TDR, RB, TDR, TDQKV);
        // gemm4: uv (bf16) into this chunk's slice of d_out
        gemm_bt<0><<<dim3(2048 / 128, RB / 128), 256, 0, stream>>>(
            t1b, TDR, wp2b, uvb, 2048, RB, 2048, TDR);
        final_k<<<RB, 256, 0, stream>>>(xb, outb);
    }
}

// Round 3
// 476.927 us; speedup vs baseline: 1.4983x; 1.4983x over previous
//
#include <hip/hip_runtime.h>
#include <hip/hip_bf16.h>

// Problem constants (B=4, T=4096, C=1024, NH=16, DH=128, DQKV=2048, DR=256)
#define TB 4
#define TT 4096
#define TC 1024
#define TNH 16
#define TDH 128
#define TDQKV 2048
#define TDR 256
#define RB 4096               // rows per batch chunk (= T)
#define ROWS (TB*TT)          // 16384

typedef __attribute__((ext_vector_type(8))) short bfx8;
typedef __attribute__((ext_vector_type(4))) float fx4;
typedef __attribute__((address_space(1))) const unsigned char GAS;
typedef __attribute__((address_space(3))) unsigned char LAS;

__device__ __forceinline__ unsigned short f2b(float f) {
    unsigned int u = __float_as_uint(f);
    unsigned int r = (u + 0x7fffu + ((u >> 16) & 1u)) >> 16;   // RNE
    return (unsigned short)r;
}
__device__ __forceinline__ float b2f(unsigned short h) {
    return __uint_as_float(((unsigned int)h) << 16);
}
__device__ __forceinline__ float sigm(float x) {
    return 1.0f / (1.0f + __expf(-x));
}

// ---------------- elementwise f32 -> bf16 (weights) ----------------
__global__ __launch_bounds__(256) void cvt_bf16(const float* __restrict__ in,
                                                unsigned short* __restrict__ out, int n) {
    int i = (blockIdx.x * 256 + threadIdx.x) * 4;
    if (i < n) {
        float4 v = *(const float4*)(in + i);
        out[i + 0] = f2b(v.x);
        out[i + 1] = f2b(v.y);
        out[i + 2] = f2b(v.z);
        out[i + 3] = f2b(v.w);
    }
}

// ---------------- RoPE cos/sin table [T][32] ----------------
__global__ __launch_bounds__(256) void rope_tab(float* __restrict__ ct, float* __restrict__ st) {
    int i = blockIdx.x * 256 + threadIdx.x;     // < T*32
    int t = i >> 5, j = i & 31;
    float fr = exp2f(-10.0f * (float)j / 31.0f);   // (1/1024)^(j/31)
    float th = (float)t * fr;
    ct[i] = cosf(th);
    st[i] = sinf(th);
}

// ---------------- RMSNorm(x) -> bf16, one block per row of 1024 ----------------
__global__ __launch_bounds__(256) void rmsnorm_x(const float* __restrict__ x,
                                                 unsigned short* __restrict__ xn) {
    int row = blockIdx.x;
    int tid = threadIdx.x;
    float4 v = *(const float4*)(x + (size_t)row * TC + tid * 4);
    float ss = v.x * v.x + v.y * v.y + v.z * v.z + v.w * v.w;
    #pragma unroll
    for (int o = 32; o > 0; o >>= 1) ss += __shfl_xor(ss, o);
    __shared__ float red[4];
    if ((tid & 63) == 0) red[tid >> 6] = ss;
    __syncthreads();
    float tot = red[0] + red[1] + red[2] + red[3];
    float sc = rsqrtf(tot * (1.0f / TC) + 1.1920929e-7f);
    unsigned short* o = xn + (size_t)row * TC + tid * 4;
    o[0] = f2b(v.x * sc); o[1] = f2b(v.y * sc); o[2] = f2b(v.z * sc); o[3] = f2b(v.w * sc);
}

// ---------------- bf16 GEMM (m97-style): C[M,N] = A[M,K](lda) @ Bm[N,K]^T ----------------
// global_load_lds width-16 staging, double-buffered linear LDS, 2-phase loop.
// M = gridDim.y*128. EPI=1: relu^2 epilogue.
template <int EPI>
__global__ __launch_bounds__(256) void gemm_bt(const unsigned short* __restrict__ A, int lda,
                                               const unsigned short* __restrict__ Bm,
                                               unsigned short* __restrict__ C, int ldc,
                                               int N, int K) {
    __shared__ unsigned short As[2][128 * 32];   // linear (global_load_lds needs contiguous dest)
    __shared__ unsigned short Bs[2][128 * 32];
    const int m0 = blockIdx.y * 128;
    const int n0 = blockIdx.x * 128;
    const int tid = threadIdx.x;
    const int lane = tid & 63;
    const int w = tid >> 6;
    const int wr = w >> 1, wc = w & 1;           // wave -> 64x64 quadrant
    const int r16 = lane & 15;
    const int kk = (lane >> 4) * 8;              // k-base of this lane's fragment
    const int l4 = lane >> 2;                    // staging: row-within-16
    const int c8 = (lane & 3) * 8;               // staging: col base
    const int nk = K >> 5;
    fx4 acc[4][4] = {};

    // stage one 128x32 A-tile and B-tile into buf: per wave 2+2 global_load_lds
    // (wave-uniform LDS base; HW scatters lane*16B; layout matches row-major [128][32])
    auto stage = [&](int buf, int k0) {
        #pragma unroll
        for (int i = 0; i < 2; ++i) {
            int rr = (w + 4 * i) * 16 + l4;
            const unsigned short* ga = A + (size_t)(m0 + rr) * lda + k0 + c8;
            const unsigned short* gb = Bm + (size_t)(n0 + rr) * K + k0 + c8;
            __builtin_amdgcn_global_load_lds((GAS*)ga, (LAS*)&As[buf][(w + 4 * i) * 512], 16, 0, 0);
            __builtin_amdgcn_global_load_lds((GAS*)gb, (LAS*)&Bs[buf][(w + 4 * i) * 512], 16, 0, 0);
        }
    };

    stage(0, 0);
    __syncthreads();                              // compiler drains vmcnt before barrier
    int buf = 0;
    for (int ks = 0; ks < nk; ++ks) {
        if (ks + 1 < nk) stage(buf ^ 1, (ks + 1) * 32);   // prefetch next tile
        bfx8 af[4], bfr[4];
        #pragma unroll
        for (int mi = 0; mi < 4; mi++) af[mi] = *(const bfx8*)&As[buf][(wr * 64 + mi * 16 + r16) * 32 + kk];
        #pragma unroll
        for (int ni = 0; ni < 4; ni++) bfr[ni] = *(const bfx8*)&Bs[buf][(wc * 64 + ni * 16 + r16) * 32 + kk];
        #pragma unroll
        for (int mi = 0; mi < 4; mi++)
            #pragma unroll
            for (int ni = 0; ni < 4; ni++)
                acc[mi][ni] = __builtin_amdgcn_mfma_f32_16x16x32_bf16(af[mi], bfr[ni], acc[mi][ni], 0, 0, 0);
        __syncthreads();                          // drain prefetch + protect buf swap
        buf ^= 1;
    }

    const int rg = lane >> 4;
    #pragma unroll
    for (int mi = 0; mi < 4; mi++)
        #pragma unroll
        for (int ni = 0; ni < 4; ni++) {
            int col = n0 + wc * 64 + ni * 16 + r16;
            #pragma unroll
            for (int r = 0; r < 4; r++) {
                int row = m0 + wr * 64 + mi * 16 + rg * 4 + r;
                float v = acc[mi][ni][r];
                if (EPI == 1) { v = fmaxf(v, 0.0f); v *= v; }
                C[(size_t)row * ldc + col] = f2b(v);
            }
        }
}

// ---------------- q/k RMSNorm + RoPE, in-place on qkv chunk (bf16), one wave per 128-row ----
// qkvb layout: [RB][6144], col = which*2048 + h*128 + d  (which: 0=q,1=k,2=v); row == t
__global__ __launch_bounds__(256) void qk_post(unsigned short* __restrict__ qkv,
                                               const float* __restrict__ ct,
                                               const float* __restrict__ st) {
    int gri = blockIdx.x * 4 + (threadIdx.x >> 6);  // < RB*32 (q heads 0-15, k heads 16-31)
    int lane = threadIdx.x & 63;
    int t = gri >> 5;
    int h32 = gri & 31;
    size_t base = (size_t)t * 6144 + (size_t)h32 * 128;
    float e0 = b2f(qkv[base + lane]);        // dim l   (z1)
    float e1 = b2f(qkv[base + 64 + lane]);   // dim l+64 (z2)
    float ss = e0 * e0 + e1 * e1;
    #pragma unroll
    for (int o = 32; o > 0; o >>= 1) ss += __shfl_xor(ss, o);
    float sc = rsqrtf(ss * (1.0f / TDH) + 1.1920929e-7f);
    float z1 = e0 * sc, z2 = e1 * sc, o1, o2;
    if (lane < 32) {
        float c = ct[t * 32 + lane], s = st[t * 32 + lane];
        o1 = z1 * c + z2 * s;
        o2 = z2 * c - z1 * s;
    } else {                                  // freq==0 -> identity
        o1 = z1; o2 = z2;
    }
    qkv[base + lane] = f2b(o1);
    qkv[base + 64 + lane] = f2b(o2);
}

// ---------------- segmented scan phase A: segment sums of sigmoid(k)*v ----------------
// blocks: h*64 + s  (16 heads x 64 segments of 64 timesteps), 128 threads = d
__global__ __launch_bounds__(128) void scanA(const unsigned short* __restrict__ qkv,
                                             float* __restrict__ part) {
    int blk = blockIdx.x;
    int d = threadIdx.x;
    int s = blk & 63;
    int h = blk >> 6;
    size_t rowbase = (size_t)(s * 64) * 6144 + (size_t)h * 128 + d;
    const unsigned short* kp = qkv + rowbase + 2048;
    const unsigned short* vp = qkv + rowbase + 4096;
    float sum = 0.0f;
    #pragma unroll 8
    for (int t = 0; t < 64; ++t) {
        float kv = b2f(kp[(size_t)t * 6144]);
        float vv = b2f(vp[(size_t)t * 6144]);
        sum += sigm(kv) * vv;
    }
    part[(size_t)blk * 128 + d] = sum;
}

// ---------------- phase B: exclusive prefix over 64 segments per (h,d), in registers ----
__global__ __launch_bounds__(256) void scanB(float* __restrict__ part) {
    int idx = blockIdx.x * 256 + threadIdx.x;   // < 2048 chains
    int h = idx >> 7, d = idx & 127;
    float v[64];
    #pragma unroll
    for (int s = 0; s < 64; ++s) v[s] = part[((size_t)(h * 64 + s)) * 128 + d];
    float run = 0.0f;
    #pragma unroll
    for (int s = 0; s < 64; ++s) { float tv = v[s]; v[s] = run; run += tv; }
    #pragma unroll
    for (int s = 0; s < 64; ++s) part[((size_t)(h * 64 + s)) * 128 + d] = v[s];
}

// ---------------- phase C: running sum + y = relu(q)*sum -> y buffer (d_out slice) --------
__global__ __launch_bounds__(128) void scanC(const unsigned short* __restrict__ qkv,
                                             const float* __restrict__ part,
                                             unsigned short* __restrict__ y) {
    int blk = blockIdx.x;
    int d = threadIdx.x;
    int s = blk & 63;
    int h = blk >> 6;
    size_t rowbase = (size_t)(s * 64) * 6144 + (size_t)h * 128 + d;
    const unsigned short* qp = qkv + rowbase;
    const unsigned short* kp = qkv + rowbase + 2048;
    const unsigned short* vp = qkv + rowbase + 4096;
    float sum = part[(size_t)blk * 128 + d];
    size_t yb = (size_t)(s * 64) * 2048 + (size_t)h * 128 + d;
    #pragma unroll 4
    for (int t = 0; t < 64; ++t) {
        float kv = b2f(kp[(size_t)t * 6144]);
        float vv = b2f(vp[(size_t)t * 6144]);
        sum += sigm(kv) * vv;
        float qv = b2f(qp[(size_t)t * 6144]);
        y[yb + (size_t)t * 2048] = f2b(fmaxf(qv, 0.0f) * sum);
    }
}

// ---------------- final: out = x + u*silu(g); uv lives in d_out (bf16), in-place per row ----
__global__ __launch_bounds__(256) void final_k(const float* __restrict__ x, float* __restrict__ out) {
    int row = blockIdx.x;
    int tid = threadIdx.x;
    const unsigned short* uv = (const unsigned short*)out;
    size_t ub = (size_t)row * 2048 + tid * 4;
    unsigned short u0 = uv[ub + 0], u1 = uv[ub + 1], u2 = uv[ub + 2], u3 = uv[ub + 3];
    unsigned short g0 = uv[ub + 1024], g1 = uv[ub + 1025], g2 = uv[ub + 1026], g3 = uv[ub + 1027];
    float4 xv = *(const float4*)(x + (size_t)row * TC + tid * 4);
    __syncthreads();   // all reads of this row done before any write (block owns the row)
    float4 o;
    {
        float g = b2f(g0), u = b2f(u0); o.x = xv.x + u * (g * sigm(g));
        g = b2f(g1); u = b2f(u1);       o.y = xv.y + u * (g * sigm(g));
        g = b2f(g2); u = b2f(u2);       o.z = xv.z + u * (g * sigm(g));
        g = b2f(g3); u = b2f(u3);       o.w = xv.w + u * (g * sigm(g));
    }
    *(float4*)(out + (size_t)row * TC + tid * 4) = o;
}

extern "C" void kernel_launch(void* const* d_in, const int* in_sizes, int n_in,
                              void* d_out, int out_size, void* d_ws, size_t ws_size,
                              hipStream_t stream) {
    (void)in_sizes; (void)n_in; (void)out_size; (void)ws_size;
    const float* x    = (const float*)d_in[0];
    const float* wq1  = (const float*)d_in[1];   // [256,1024]
    const float* wq2  = (const float*)d_in[2];   // [6144,256]
    const float* wc1  = (const float*)d_in[3];   // [256,2048]
    const float* wc2  = (const float*)d_in[4];   // [2048,256]
    float* out = (float*)d_out;

    char* ws = (char*)d_ws;
    size_t off = 0;
    auto alloc = [&](size_t bytes) -> void* {
        off = (off + 255) & ~(size_t)255;
        void* p = ws + off;
        off += bytes;
        return p;
    };
    // pool: max(qkvb 50.3, xn 33.5, t1 8.4) -- live ranges disjoint:
    //   xn: rmsnorm -> gemm1;  qkvb: gemm2(b) -> scanC(b);  t1: gemm3 -> gemm4
    char* pool = (char*)alloc((size_t)RB * 6144 * 2);          // 50.3 MB
    unsigned short* qkvb = (unsigned short*)pool;
    unsigned short* xn   = (unsigned short*)pool;              // alias (ROWS x 1024)
    unsigned short* t1   = (unsigned short*)pool;              // alias (ROWS x 256)
    unsigned short* hbuf = (unsigned short*)alloc((size_t)ROWS * TDR * 2);      // 8.4 MB
    unsigned short* w1b  = (unsigned short*)alloc((size_t)TDR * TC * 2);
    unsigned short* w2b  = (unsigned short*)alloc((size_t)3 * TDQKV * TDR * 2);
    unsigned short* wp1b = (unsigned short*)alloc((size_t)TDR * TDQKV * 2);
    unsigned short* wp2b = (unsigned short*)alloc((size_t)2 * TC * TDR * 2);
    float* ct   = (float*)alloc((size_t)TT * 32 * 4);
    float* st   = (float*)alloc((size_t)TT * 32 * 4);
    float* part = (float*)alloc((size_t)TNH * 64 * 128 * 4);   // 0.5 MB
    unsigned short* ybuf = (unsigned short*)d_out;             // y/uv live in d_out (bf16 16384x2048)

    // setup (per call; cheap)
    cvt_bf16<<<(TDR * TC) / 1024, 256, 0, stream>>>(wq1, w1b, TDR * TC);
    cvt_bf16<<<(3 * TDQKV * TDR) / 1024, 256, 0, stream>>>(wq2, w2b, 3 * TDQKV * TDR);
    cvt_bf16<<<(TDR * TDQKV) / 1024, 256, 0, stream>>>(wc1, wp1b, TDR * TDQKV);
    cvt_bf16<<<(2 * TC * TDR) / 1024, 256, 0, stream>>>(wc2, wp2b, 2 * TC * TDR);
    rope_tab<<<(TT * 32) / 256, 256, 0, stream>>>(ct, st);

    // all-rows: rmsnorm + gemm1 (xn -> h), xn in pool (dead before qkvb first written)
    rmsnorm_x<<<ROWS, 256, 0, stream>>>(x, xn);
    gemm_bt<1><<<dim3(TDR / 128, ROWS / 128), 256, 0, stream>>>(
        xn, TC, w1b, hbuf, TDR, TDR, TC);

    // per-batch-chunk: gemm2 -> qk_post -> scan; y goes to d_out slice
    for (int b = 0; b < TB; ++b) {
        gemm_bt<0><<<dim3(6144 / 128, RB / 128), 256, 0, stream>>>(
            hbuf + (size_t)b * RB * TDR, TDR, w2b, qkvb, 6144, 6144, TDR);
        qk_post<<<(RB * 32) / 4, 256, 0, stream>>>(qkvb, ct, st);
        scanA<<<TNH * 64, 128, 0, stream>>>(qkvb, part);
        scanB<<<(TNH * 128) / 256, 256, 0, stream>>>(part);
        scanC<<<TNH * 64, 128, 0, stream>>>(qkvb, part, ybuf + (size_t)b * RB * 2048);
    }

    // all-rows tail: gemm3 (y -> t1), gemm4 (t1 -> uv in d_out), final
    gemm_bt<0><<<dim3(TDR / 128, ROWS / 128), 256, 0, stream>>>(
        ybuf, 2048, wp1b, t1, TDR, TDR, TDQKV);
    gemm_bt<0><<<dim3(2048 / 128, ROWS / 128), 256, 0, stream>>>(
        t1, TDR, wp2b, (unsigned short*)d_out, 2048, 2048, TDR);
    final_k<<<ROWS, 256, 0, stream>>>(x, out);
}

// Round 4
// 412.359 us; speedup vs baseline: 1.7330x; 1.1566x over previous
//
#include <hip/hip_runtime.h>
#include <hip/hip_bf16.h>

// Problem constants (B=4, T=4096, C=1024, NH=16, DH=128, DQKV=2048, DR=256)
#define TB 4
#define TT 4096
#define TC 1024
#define TNH 16
#define TDH 128
#define TDQKV 2048
#define TDR 256
#define RB 4096               // rows per batch chunk (= T)
#define ROWS (TB*TT)          // 16384
#define SLAB (RB*128)         // shorts per head-slab (one chunk)

typedef __attribute__((ext_vector_type(8))) short bfx8;
typedef __attribute__((ext_vector_type(4))) float fx4;
typedef __attribute__((address_space(1))) const unsigned char GAS;
typedef __attribute__((address_space(3))) unsigned char LAS;

__device__ __forceinline__ unsigned short f2b(float f) {
    unsigned int u = __float_as_uint(f);
    unsigned int r = (u + 0x7fffu + ((u >> 16) & 1u)) >> 16;   // RNE
    return (unsigned short)r;
}
__device__ __forceinline__ float b2f(unsigned short h) {
    return __uint_as_float(((unsigned int)h) << 16);
}
__device__ __forceinline__ float sigm(float x) {
    return 1.0f / (1.0f + __expf(-x));
}
// bijective XCD swizzle (nwg % 8 == 0 in all our grids)
__device__ __forceinline__ int xcd_swz(int hw, int nwg) {
    int q = nwg >> 3;
    return (hw & 7) * q + (hw >> 3);
}

// ---------------- elementwise f32 -> bf16 (weights) ----------------
__global__ __launch_bounds__(256) void cvt_bf16(const float* __restrict__ in,
                                                unsigned short* __restrict__ out, int n) {
    int i = (blockIdx.x * 256 + threadIdx.x) * 4;
    if (i < n) {
        float4 v = *(const float4*)(in + i);
        out[i + 0] = f2b(v.x);
        out[i + 1] = f2b(v.y);
        out[i + 2] = f2b(v.z);
        out[i + 3] = f2b(v.w);
    }
}

// ---------------- RoPE cos/sin table [T][32] ----------------
__global__ __launch_bounds__(256) void rope_tab(float* __restrict__ ct, float* __restrict__ st) {
    int i = blockIdx.x * 256 + threadIdx.x;     // < T*32
    int t = i >> 5, j = i & 31;
    float fr = exp2f(-10.0f * (float)j / 31.0f);   // (1/1024)^(j/31)
    float th = (float)t * fr;
    ct[i] = cosf(th);
    st[i] = sinf(th);
}

// ---------------- RMSNorm(x) -> bf16, one block per row of 1024 ----------------
__global__ __launch_bounds__(256) void rmsnorm_x(const float* __restrict__ x,
                                                 unsigned short* __restrict__ xn) {
    int row = blockIdx.x;
    int tid = threadIdx.x;
    float4 v = *(const float4*)(x + (size_t)row * TC + tid * 4);
    float ss = v.x * v.x + v.y * v.y + v.z * v.z + v.w * v.w;
    #pragma unroll
    for (int o = 32; o > 0; o >>= 1) ss += __shfl_xor(ss, o);
    __shared__ float red[4];
    if ((tid & 63) == 0) red[tid >> 6] = ss;
    __syncthreads();
    float tot = red[0] + red[1] + red[2] + red[3];
    float sc = rsqrtf(tot * (1.0f / TC) + 1.1920929e-7f);
    unsigned short* o = xn + (size_t)row * TC + tid * 4;
    o[0] = f2b(v.x * sc); o[1] = f2b(v.y * sc); o[2] = f2b(v.z * sc); o[3] = f2b(v.w * sc);
}

// ---------------- 128x128 bf16 GEMM (m97 2-phase), EPI=2: scatter to head-major qkv ----
// C layout (EPI=2): slab head_idx = col>>7 (48 slabs), addr = head*SLAB + row*128 + (col&127)
template <int EPI>
__global__ __launch_bounds__(256) void gemm_bt(const unsigned short* __restrict__ A, int lda,
                                               const unsigned short* __restrict__ Bm,
                                               unsigned short* __restrict__ C, int ldc,
                                               int N, int K) {
    __shared__ unsigned short As[2][128 * 32];
    __shared__ unsigned short Bs[2][128 * 32];
    const int m0 = blockIdx.y * 128;
    const int n0 = blockIdx.x * 128;
    const int tid = threadIdx.x;
    const int lane = tid & 63;
    const int w = tid >> 6;
    const int wr = w >> 1, wc = w & 1;
    const int r16 = lane & 15;
    const int kk = (lane >> 4) * 8;
    const int l4 = lane >> 2;
    const int c8 = (lane & 3) * 8;
    const int nk = K >> 5;
    fx4 acc[4][4] = {};

    auto stage = [&](int buf, int k0) {
        #pragma unroll
        for (int i = 0; i < 2; ++i) {
            int rr = (w + 4 * i) * 16 + l4;
            const unsigned short* ga = A + (size_t)(m0 + rr) * lda + k0 + c8;
            const unsigned short* gb = Bm + (size_t)(n0 + rr) * K + k0 + c8;
            __builtin_amdgcn_global_load_lds((GAS*)ga, (LAS*)&As[buf][(w + 4 * i) * 512], 16, 0, 0);
            __builtin_amdgcn_global_load_lds((GAS*)gb, (LAS*)&Bs[buf][(w + 4 * i) * 512], 16, 0, 0);
        }
    };

    stage(0, 0);
    __syncthreads();
    int buf = 0;
    for (int ks = 0; ks < nk; ++ks) {
        if (ks + 1 < nk) stage(buf ^ 1, (ks + 1) * 32);
        bfx8 af[4], bfr[4];
        #pragma unroll
        for (int mi = 0; mi < 4; mi++) af[mi] = *(const bfx8*)&As[buf][(wr * 64 + mi * 16 + r16) * 32 + kk];
        #pragma unroll
        for (int ni = 0; ni < 4; ni++) bfr[ni] = *(const bfx8*)&Bs[buf][(wc * 64 + ni * 16 + r16) * 32 + kk];
        #pragma unroll
        for (int mi = 0; mi < 4; mi++)
            #pragma unroll
            for (int ni = 0; ni < 4; ni++)
                acc[mi][ni] = __builtin_amdgcn_mfma_f32_16x16x32_bf16(af[mi], bfr[ni], acc[mi][ni], 0, 0, 0);
        __syncthreads();
        buf ^= 1;
    }

    const int rg = lane >> 4;
    #pragma unroll
    for (int mi = 0; mi < 4; mi++)
        #pragma unroll
        for (int ni = 0; ni < 4; ni++) {
            int col = n0 + wc * 64 + ni * 16 + r16;
            #pragma unroll
            for (int r = 0; r < 4; r++) {
                int row = m0 + wr * 64 + mi * 16 + rg * 4 + r;
                float v = acc[mi][ni][r];
                if (EPI == 1) { v = fmaxf(v, 0.0f); v *= v; }
                if (EPI == 2) {
                    int head = col >> 7;
                    C[(size_t)head * SLAB + (size_t)row * 128 + (col & 127)] = f2b(v);
                } else {
                    C[(size_t)row * ldc + col] = f2b(v);
                }
            }
        }
}

// ---------------- 64x64-tile GEMM for skinny N (grid = (N/64, M/64), XCD-swizzled) ------
// 4 waves -> 32x32 quadrants, 2x2 16x16 frags; 2-phase global_load_lds pipeline.
template <int EPI, int NX>
__global__ __launch_bounds__(256) void gemm_bt64(const unsigned short* __restrict__ A, int lda,
                                                 const unsigned short* __restrict__ Bm,
                                                 unsigned short* __restrict__ C, int ldc,
                                                 int K) {
    __shared__ unsigned short As[2][64 * 32];
    __shared__ unsigned short Bs[2][64 * 32];
    const int hw = blockIdx.y * gridDim.x + blockIdx.x;
    const int lg = xcd_swz(hw, gridDim.x * gridDim.y);
    const int n0 = (lg % NX) * 64;
    const int m0 = (lg / NX) * 64;
    const int tid = threadIdx.x;
    const int lane = tid & 63;
    const int w = tid >> 6;
    const int wr = w >> 1, wc = w & 1;
    const int r16 = lane & 15;
    const int kk = (lane >> 4) * 8;
    const int l4 = lane >> 2;
    const int c8 = (lane & 3) * 8;
    const int nk = K >> 5;
    fx4 acc[2][2] = {};

    auto stage = [&](int buf, int k0) {
        int rr = w * 16 + l4;
        const unsigned short* ga = A + (size_t)(m0 + rr) * lda + k0 + c8;
        const unsigned short* gb = Bm + (size_t)(n0 + rr) * K + k0 + c8;
        __builtin_amdgcn_global_load_lds((GAS*)ga, (LAS*)&As[buf][w * 512], 16, 0, 0);
        __builtin_amdgcn_global_load_lds((GAS*)gb, (LAS*)&Bs[buf][w * 512], 16, 0, 0);
    };

    stage(0, 0);
    __syncthreads();
    int buf = 0;
    for (int ks = 0; ks < nk; ++ks) {
        if (ks + 1 < nk) stage(buf ^ 1, (ks + 1) * 32);
        bfx8 af[2], bfr[2];
        #pragma unroll
        for (int mi = 0; mi < 2; mi++) af[mi] = *(const bfx8*)&As[buf][(wr * 32 + mi * 16 + r16) * 32 + kk];
        #pragma unroll
        for (int ni = 0; ni < 2; ni++) bfr[ni] = *(const bfx8*)&Bs[buf][(wc * 32 + ni * 16 + r16) * 32 + kk];
        #pragma unroll
        for (int mi = 0; mi < 2; mi++)
            #pragma unroll
            for (int ni = 0; ni < 2; ni++)
                acc[mi][ni] = __builtin_amdgcn_mfma_f32_16x16x32_bf16(af[mi], bfr[ni], acc[mi][ni], 0, 0, 0);
        __syncthreads();
        buf ^= 1;
    }

    const int rg = lane >> 4;
    #pragma unroll
    for (int mi = 0; mi < 2; mi++)
        #pragma unroll
        for (int ni = 0; ni < 2; ni++) {
            int col = n0 + wc * 32 + ni * 16 + r16;
            #pragma unroll
            for (int r = 0; r < 4; r++) {
                int row = m0 + wr * 32 + mi * 16 + rg * 4 + r;
                float v = acc[mi][ni][r];
                if (EPI == 1) { v = fmaxf(v, 0.0f); v *= v; }
                C[(size_t)row * ldc + col] = f2b(v);
            }
        }
}

// ---------------- gemm4 fused with final: out = x + u*silu(g), f32 ----------------
// A = t1 [ROWS][256], W = wp2b [2048][256]; block computes u-tile (n0) and g-tile (n0+1024).
__global__ __launch_bounds__(256, 2) void gemm4f(const unsigned short* __restrict__ A,
                                                 const unsigned short* __restrict__ Wm,
                                                 const float* __restrict__ x,
                                                 float* __restrict__ out) {
    __shared__ unsigned short As[2][128 * 32];
    __shared__ unsigned short Bu[2][128 * 32];
    __shared__ unsigned short Bg[2][128 * 32];
    const int hw = blockIdx.y * gridDim.x + blockIdx.x;
    const int lg = xcd_swz(hw, gridDim.x * gridDim.y);
    const int n0 = (lg & 7) * 128;           // u col block within 1024
    const int m0 = (lg >> 3) * 128;
    const int tid = threadIdx.x;
    const int lane = tid & 63;
    const int w = tid >> 6;
    const int wr = w >> 1, wc = w & 1;
    const int r16 = lane & 15;
    const int kk = (lane >> 4) * 8;
    const int l4 = lane >> 2;
    const int c8 = (lane & 3) * 8;
    fx4 accu[4][4] = {};
    fx4 accg[4][4] = {};

    auto stage = [&](int buf, int k0) {
        #pragma unroll
        for (int i = 0; i < 2; ++i) {
            int rr = (w + 4 * i) * 16 + l4;
            const unsigned short* ga = A + (size_t)(m0 + rr) * TDR + k0 + c8;
            const unsigned short* gu = Wm + (size_t)(n0 + rr) * TDR + k0 + c8;
            const unsigned short* gg = Wm + (size_t)(1024 + n0 + rr) * TDR + k0 + c8;
            __builtin_amdgcn_global_load_lds((GAS*)ga, (LAS*)&As[buf][(w + 4 * i) * 512], 16, 0, 0);
            __builtin_amdgcn_global_load_lds((GAS*)gu, (LAS*)&Bu[buf][(w + 4 * i) * 512], 16, 0, 0);
            __builtin_amdgcn_global_load_lds((GAS*)gg, (LAS*)&Bg[buf][(w + 4 * i) * 512], 16, 0, 0);
        }
    };

    stage(0, 0);
    __syncthreads();
    int buf = 0;
    for (int ks = 0; ks < 8; ++ks) {          // K = 256
        if (ks + 1 < 8) stage(buf ^ 1, (ks + 1) * 32);
        bfx8 af[4], bu[4], bg[4];
        #pragma unroll
        for (int mi = 0; mi < 4; mi++) af[mi] = *(const bfx8*)&As[buf][(wr * 64 + mi * 16 + r16) * 32 + kk];
        #pragma unroll
        for (int ni = 0; ni < 4; ni++) {
            bu[ni] = *(const bfx8*)&Bu[buf][(wc * 64 + ni * 16 + r16) * 32 + kk];
            bg[ni] = *(const bfx8*)&Bg[buf][(wc * 64 + ni * 16 + r16) * 32 + kk];
        }
        #pragma unroll
        for (int mi = 0; mi < 4; mi++)
            #pragma unroll
            for (int ni = 0; ni < 4; ni++) {
                accu[mi][ni] = __builtin_amdgcn_mfma_f32_16x16x32_bf16(af[mi], bu[ni], accu[mi][ni], 0, 0, 0);
                accg[mi][ni] = __builtin_amdgcn_mfma_f32_16x16x32_bf16(af[mi], bg[ni], accg[mi][ni], 0, 0, 0);
            }
        __syncthreads();
        buf ^= 1;
    }

    const int rg = lane >> 4;
    #pragma unroll
    for (int mi = 0; mi < 4; mi++)
        #pragma unroll
        for (int ni = 0; ni < 4; ni++) {
            int col = n0 + wc * 64 + ni * 16 + r16;      // < 1024
            #pragma unroll
            for (int r = 0; r < 4; r++) {
                int row = m0 + wr * 64 + mi * 16 + rg * 4 + r;
                float u = accu[mi][ni][r];
                float g = accg[mi][ni][r];
                size_t idx = (size_t)row * TC + col;
                out[idx] = x[idx] + u * (g * sigm(g));
            }
        }
}

// ---------------- q/k RMSNorm + RoPE on head-major qkv, one wave per (slab,t) row ------
// slabs: h32 in [0,32): 0-15 = q heads, 16-31 = k heads; row = h32*SLAB + t*128
__global__ __launch_bounds__(256) void qk_post(unsigned short* __restrict__ qkv,
                                               const float* __restrict__ ct,
                                               const float* __restrict__ st) {
    int gri = blockIdx.x * 4 + (threadIdx.x >> 6);   // < 32*RB
    int lane = threadIdx.x & 63;
    int h32 = gri >> 12;
    int t = gri & (RB - 1);
    size_t base = (size_t)h32 * SLAB + (size_t)t * 128;
    float e0 = b2f(qkv[base + lane]);        // dim l   (z1)
    float e1 = b2f(qkv[base + 64 + lane]);   // dim l+64 (z2)
    float ss = e0 * e0 + e1 * e1;
    #pragma unroll
    for (int o = 32; o > 0; o >>= 1) ss += __shfl_xor(ss, o);
    float sc = rsqrtf(ss * (1.0f / TDH) + 1.1920929e-7f);
    float z1 = e0 * sc, z2 = e1 * sc, o1, o2;
    if (lane < 32) {
        float c = ct[t * 32 + lane], s = st[t * 32 + lane];
        o1 = z1 * c + z2 * s;
        o2 = z2 * c - z1 * s;
    } else {                                  // freq==0 -> identity
        o1 = z1; o2 = z2;
    }
    qkv[base + lane] = f2b(o1);
    qkv[base + 64 + lane] = f2b(o2);
}

// ---------------- segmented scan phase A: segment sums of sigmoid(k)*v (head-major) ----
__global__ __launch_bounds__(128) void scanA(const unsigned short* __restrict__ qkv,
                                             float* __restrict__ part) {
    int blk = blockIdx.x;          // h*64 + s
    int d = threadIdx.x;
    int s = blk & 63;
    int h = blk >> 6;
    const unsigned short* kp = qkv + (size_t)(16 + h) * SLAB + (size_t)(s * 64) * 128 + d;
    const unsigned short* vp = qkv + (size_t)(32 + h) * SLAB + (size_t)(s * 64) * 128 + d;
    float sum = 0.0f;
    #pragma unroll 8
    for (int t = 0; t < 64; ++t) {
        float kv = b2f(kp[t * 128]);
        float vv = b2f(vp[t * 128]);
        sum += sigm(kv) * vv;
    }
    part[(size_t)blk * 128 + d] = sum;
}

// ---------------- phase B: exclusive prefix over 64 segments per (h,d), in registers ----
__global__ __launch_bounds__(256) void scanB(float* __restrict__ part) {
    int idx = blockIdx.x * 256 + threadIdx.x;   // < 2048 chains
    int h = idx >> 7, d = idx & 127;
    float v[64];
    #pragma unroll
    for (int s = 0; s < 64; ++s) v[s] = part[((size_t)(h * 64 + s)) * 128 + d];
    float run = 0.0f;
    #pragma unroll
    for (int s = 0; s < 64; ++s) { float tv = v[s]; v[s] = run; run += tv; }
    #pragma unroll
    for (int s = 0; s < 64; ++s) part[((size_t)(h * 64 + s)) * 128 + d] = v[s];
}

// ---------------- phase C: running sum + y = relu(q)*sum -> y row-major (d_out slice) ---
__global__ __launch_bounds__(128) void scanC(const unsigned short* __restrict__ qkv,
                                             const float* __restrict__ part,
                                             unsigned short* __restrict__ y) {
    int blk = blockIdx.x;
    int d = threadIdx.x;
    int s = blk & 63;
    int h = blk >> 6;
    const unsigned short* qp = qkv + (size_t)h * SLAB + (size_t)(s * 64) * 128 + d;
    const unsigned short* kp = qkv + (size_t)(16 + h) * SLAB + (size_t)(s * 64) * 128 + d;
    const unsigned short* vp = qkv + (size_t)(32 + h) * SLAB + (size_t)(s * 64) * 128 + d;
    float sum = part[(size_t)blk * 128 + d];
    size_t yb = (size_t)(s * 64) * 2048 + (size_t)h * 128 + d;
    #pragma unroll 4
    for (int t = 0; t < 64; ++t) {
        float kv = b2f(kp[t * 128]);
        float vv = b2f(vp[t * 128]);
        sum += sigm(kv) * vv;
        float qv = b2f(qp[t * 128]);
        y[yb + (size_t)t * 2048] = f2b(fmaxf(qv, 0.0f) * sum);
    }
}

extern "C" void kernel_launch(void* const* d_in, const int* in_sizes, int n_in,
                              void* d_out, int out_size, void* d_ws, size_t ws_size,
                              hipStream_t stream) {
    (void)in_sizes; (void)n_in; (void)out_size; (void)ws_size;
    const float* x    = (const float*)d_in[0];
    const float* wq1  = (const float*)d_in[1];   // [256,1024]
    const float* wq2  = (const float*)d_in[2];   // [6144,256]
    const float* wc1  = (const float*)d_in[3];   // [256,2048]
    const float* wc2  = (const float*)d_in[4];   // [2048,256]
    float* out = (float*)d_out;

    char* ws = (char*)d_ws;
    size_t off = 0;
    auto alloc = [&](size_t bytes) -> void* {
        off = (off + 255) & ~(size_t)255;
        void* p = ws + off;
        off += bytes;
        return p;
    };
    // pool: max(qkvb 50.3, xn 33.5, t1 8.4) MB -- live ranges disjoint
    char* pool = (char*)alloc((size_t)RB * 6144 * 2);          // 50.3 MB
    unsigned short* qkvb = (unsigned short*)pool;              // head-major: 48 slabs [RB][128]
    unsigned short* xn   = (unsigned short*)pool;              // alias (ROWS x 1024)
    unsigned short* t1   = (unsigned short*)pool;              // alias (ROWS x 256)
    unsigned short* hbuf = (unsigned short*)alloc((size_t)ROWS * TDR * 2);      // 8.4 MB
    unsigned short* w1b  = (unsigned short*)alloc((size_t)TDR * TC * 2);
    unsigned short* w2b  = (unsigned short*)alloc((size_t)3 * TDQKV * TDR * 2);
    unsigned short* wp1b = (unsigned short*)alloc((size_t)TDR * TDQKV * 2);
    unsigned short* wp2b = (unsigned short*)alloc((size_t)2 * TC * TDR * 2);
    float* ct   = (float*)alloc((size_t)TT * 32 * 4);
    float* st   = (float*)alloc((size_t)TT * 32 * 4);
    float* part = (float*)alloc((size_t)TNH * 64 * 128 * 4);   // 0.5 MB
    unsigned short* ybuf = (unsigned short*)d_out;             // y lives in d_out (bf16 16384x2048)

    // setup (per call; cheap)
    cvt_bf16<<<(TDR * TC) / 1024, 256, 0, stream>>>(wq1, w1b, TDR * TC);
    cvt_bf16<<<(3 * TDQKV * TDR) / 1024, 256, 0, stream>>>(wq2, w2b, 3 * TDQKV * TDR);
    cvt_bf16<<<(TDR * TDQKV) / 1024, 256, 0, stream>>>(wc1, wp1b, TDR * TDQKV);
    cvt_bf16<<<(2 * TC * TDR) / 1024, 256, 0, stream>>>(wc2, wp2b, 2 * TC * TDR);
    rope_tab<<<(TT * 32) / 256, 256, 0, stream>>>(ct, st);

    // all-rows: rmsnorm + gemm1 (xn -> h) with relu^2
    rmsnorm_x<<<ROWS, 256, 0, stream>>>(x, xn);
    gemm_bt64<1, 4><<<dim3(TDR / 64, ROWS / 64), 256, 0, stream>>>(
        xn, TC, w1b, hbuf, TDR, TC);

    // per-batch-chunk: gemm2 (scatter to head-major) -> qk_post -> scan; y -> d_out slice
    for (int b = 0; b < TB; ++b) {
        gemm_bt<2><<<dim3(6144 / 128, RB / 128), 256, 0, stream>>>(
            hbuf + (size_t)b * RB * TDR, TDR, w2b, qkvb, 0, 6144, TDR);
        qk_post<<<(RB * 32) / 4, 256, 0, stream>>>(qkvb, ct, st);
        scanA<<<TNH * 64, 128, 0, stream>>>(qkvb, part);
        scanB<<<(TNH * 128) / 256, 256, 0, stream>>>(part);
        scanC<<<TNH * 64, 128, 0, stream>>>(qkvb, part, ybuf + (size_t)b * RB * 2048);
    }

    // all-rows tail: gemm3 (y -> t1), fused gemm4+final -> f32 out
    gemm_bt64<0, 4><<<dim3(TDR / 64, ROWS / 64), 256, 0, stream>>>(
        ybuf, 2048, wp1b, t1, TDR, TDQKV);
    gemm4f<<<dim3(TC / 128, ROWS / 128), 256, 0, stream>>>(t1, wp2b, x, out);
}